// Round 12
// baseline (347.170 us; speedup 1.0000x reference)
//
#include <hip/hip_runtime.h>
#include <hip/hip_bf16.h>
#include <stdint.h>

// Net_61272003445332: GraphSAGE w/ LSTM aggregator, N=20000, K=16,
// dims: l0 (din=64,dout=128), l1 (128,128), l2 (128,32).
// R11: (a) lstm_fc_kern templated on NT row-tiles per block. DIN=64 -> NT=2
//      (32 nodes/block: half the barriers, MFMA(nt1) overlaps gates(nt0);
//      safe: Bp only 32 regs there). DIN=128 stays NT=1 (combined reg use
//      ~128 = the waves_per_eu(4) budget; NT=2 would spill — R8/R9 lesson:
//      VGPR_Count hides AGPR-resident Bp).
//      (b) 3x cvt4 launches merged into one cvt_all (13 -> 8 dispatches).

#define N_NODES 20000
#define KNE 16

typedef __bf16 bf16x8 __attribute__((ext_vector_type(8)));
typedef float f32x4 __attribute__((ext_vector_type(4)));

__device__ __forceinline__ bf16x8 ldb8(const __hip_bfloat16* p) {
  uint4 u = *reinterpret_cast<const uint4*>(p);
  return __builtin_bit_cast(bf16x8, u);
}
// Anti-rematerialization pin: per-32-bit-word no-op asm.
__device__ __forceinline__ void pin(bf16x8& v) {
  uint4 u = __builtin_bit_cast(uint4, v);
  asm volatile("" : "+v"(u.x), "+v"(u.y), "+v"(u.z), "+v"(u.w));
  v = __builtin_bit_cast(bf16x8, u);
}
__device__ __forceinline__ float b2f_lo(uint32_t u) {
  return __builtin_bit_cast(float, u << 16);
}
__device__ __forceinline__ float b2f_hi(uint32_t u) {
  return __builtin_bit_cast(float, u & 0xffff0000u);
}
__device__ __forceinline__ uint32_t pk2(float a, float b) {
  uint32_t ua = (uint32_t)__builtin_bit_cast(unsigned short, __float2bfloat16(a));
  uint32_t ub = (uint32_t)__builtin_bit_cast(unsigned short, __float2bfloat16(b));
  return ua | (ub << 16);
}
// NaN-safe, clamp-free saturating forms.
__device__ __forceinline__ float sigf(float x) {
  float t = __builtin_amdgcn_exp2f(-1.442695041f * x);
  return __builtin_amdgcn_rcpf(1.f + t);
}
__device__ __forceinline__ float tanhf_(float x) {
  float t = __builtin_amdgcn_exp2f(2.885390082f * x);
  return 1.f - 2.f * __builtin_amdgcn_rcpf(t + 1.f);
}

__global__ void build_feat0(const float* __restrict__ p,
                            __hip_bfloat16* __restrict__ f0) {
  int i = blockIdx.x * 256 + threadIdx.x;
  if (i >= N_NODES * 64) return;
  int n = i >> 6, c = i & 63;
  float v = (c == 0) ? ((float)KNE / (float)N_NODES) : p[n * 63 + c - 1];
  f0[i] = __float2bfloat16(v);
}

// All 12 weight tensors fp32->bf16 in one launch.
struct CvtArgs {
  const float* s[12];
  __hip_bfloat16* d[12];
  int off[13];  // exclusive prefix sums; off[12] = total
};
__global__ void cvt_all(CvtArgs a) {
  int i = blockIdx.x * 256 + threadIdx.x;
  if (i >= a.off[12]) return;
#pragma unroll
  for (int k = 0; k < 12; ++k)
    if (i >= a.off[k] && i < a.off[k + 1]) {
      int j = i - a.off[k];
      a.d[k][j] = __float2bfloat16(a.s[k][j]);
    }
}

// P = feat@Wih.T + (bih+bhh) -> bf16 GATE-PACKED: P[n][cc*4+g] (uint2/col)
// S = feat@Wself.T + b       -> f32 [N,DOUT]
template <int DIN, int DOUT>
__global__ __launch_bounds__(256, 2) void proj_kern(
    const __hip_bfloat16* __restrict__ feat,
    const __hip_bfloat16* __restrict__ Wih,   // bf16 [4*DIN, DIN]
    const float* __restrict__ bih,
    const float* __restrict__ bhh,
    const __hip_bfloat16* __restrict__ Wself, // bf16 [DOUT, DIN]
    const float* __restrict__ bvec,
    __hip_bfloat16* __restrict__ P, float* __restrict__ S) {
  constexpr int KB = DIN / 32;
  constexpr int CCT = DIN / 16;    // packed-P col tiles
  constexpr int CTS = DOUT / 16;   // S col tiles
  const int n0 = blockIdx.x * 32;
  const int tid = threadIdx.x;
  const int wv = tid >> 6;
  const int lane = tid & 63;
  const int quad = lane >> 4;
  const int c16 = lane & 15;

  bf16x8 afr[2][KB];
#pragma unroll
  for (int rt = 0; rt < 2; ++rt)
#pragma unroll
    for (int kb = 0; kb < KB; ++kb)
      afr[rt][kb] =
          ldb8(feat + (size_t)(n0 + rt * 16 + c16) * DIN + kb * 32 + quad * 8);

  const f32x4 zz = {0.f, 0.f, 0.f, 0.f};
  for (int ct = wv; ct < CCT + CTS; ct += 4) {
    if (ct < CCT) {
      const int cc = ct * 16 + c16;
      f32x4 ag[4][2];
#pragma unroll
      for (int g = 0; g < 4; ++g) { ag[g][0] = zz; ag[g][1] = zz; }
#pragma unroll
      for (int kb = 0; kb < KB; ++kb)
#pragma unroll
        for (int g = 0; g < 4; ++g) {
          bf16x8 b = ldb8(Wih + (size_t)(g * DIN + cc) * DIN + kb * 32 +
                          quad * 8);
          ag[g][0] = __builtin_amdgcn_mfma_f32_16x16x32_bf16(afr[0][kb], b,
                                                             ag[g][0], 0, 0, 0);
          ag[g][1] = __builtin_amdgcn_mfma_f32_16x16x32_bf16(afr[1][kb], b,
                                                             ag[g][1], 0, 0, 0);
        }
      float bi = bih[cc] + bhh[cc];
      float bff = bih[DIN + cc] + bhh[DIN + cc];
      float bg = bih[2 * DIN + cc] + bhh[2 * DIN + cc];
      float bo = bih[3 * DIN + cc] + bhh[3 * DIN + cc];
      uint2* Pp = reinterpret_cast<uint2*>(P);
#pragma unroll
      for (int rt = 0; rt < 2; ++rt)
#pragma unroll
        for (int r = 0; r < 4; ++r) {
          int n = n0 + rt * 16 + quad * 4 + r;
          uint2 u;
          u.x = pk2(ag[0][rt][r] + bi, ag[1][rt][r] + bff);
          u.y = pk2(ag[2][rt][r] + bg, ag[3][rt][r] + bo);
          Pp[(size_t)n * DIN + cc] = u;
        }
    } else {
      const int c = (ct - CCT) * 16 + c16;
      f32x4 a0 = zz, a1 = zz;
#pragma unroll
      for (int kb = 0; kb < KB; ++kb) {
        bf16x8 b = ldb8(Wself + (size_t)c * DIN + kb * 32 + quad * 8);
        a0 = __builtin_amdgcn_mfma_f32_16x16x32_bf16(afr[0][kb], b, a0, 0, 0, 0);
        a1 = __builtin_amdgcn_mfma_f32_16x16x32_bf16(afr[1][kb], b, a1, 0, 0, 0);
      }
      float bias = bvec[c];
#pragma unroll
      for (int r = 0; r < 4; ++r) {
        S[(size_t)(n0 + quad * 4 + r) * DOUT + c] = a0[r] + bias;
        S[(size_t)(n0 + 16 + quad * 4 + r) * DOUT + c] = a1[r] + bias;
      }
    }
  }
}

// LSTM + fused fc. Block = (DIN/16) waves, NT 16-node row-tiles (16*NT nodes).
// Wave wv owns cols [wv*16, wv*16+16) of ALL 4 gates; Whh frags pinned
// (AGPR-resident). pf gathers double-buffered; t-loop fully unrolled;
// MFMA accumulators initialized with gate pre-activations.
template <int DIN, int DOUT, int NT, bool RELU, typename OutT>
__global__ __launch_bounds__((DIN / 16) * 64)
__attribute__((amdgpu_waves_per_eu(4))) void lstm_fc_kern(
    const __hip_bfloat16* __restrict__ P,   // [N][DIN][4] gate-packed bf16
    const float* __restrict__ S,            // [N, DOUT] f32
    const __hip_bfloat16* __restrict__ Whh, // bf16 [4*DIN, DIN]
    const __hip_bfloat16* __restrict__ Wng, // bf16 [DOUT, DIN]
    const int* __restrict__ nidx,           // [N, 16]
    OutT* __restrict__ outp) {              // [N, DOUT]
  constexpr int W = DIN / 16;    // waves per block
  constexpr int KB = DIN / 32;   // MFMA K blocks
  constexpr int HS = DIN + 8;    // h row stride
  constexpr int NN = 16 * NT;    // nodes per block

  __shared__ __align__(16) __hip_bfloat16 hl[2][NN * HS];
  __shared__ int idxl[NN * KNE];

  const int n0 = blockIdx.x * NN;
  const int tid = threadIdx.x;
  const int wv = tid >> 6;
  const int lane = tid & 63;
  const int quad = lane >> 4;
  const int c16 = lane & 15;
  const int col = wv * 16 + c16;  // this lane's h/gate column

  for (int i = tid; i < NN * KNE; i += W * 64) idxl[i] = nidx[n0 * KNE + i];
  __syncthreads();  // idxl ready

  uint2 pf[2][NT][4];
  auto loadpf = [&](int t, int b) {
#pragma unroll
    for (int nt = 0; nt < NT; ++nt)
#pragma unroll
      for (int r = 0; r < 4; ++r) {
        int src = idxl[(nt * 16 + quad * 4 + r) * KNE + t];
        pf[b][nt][r] =
            reinterpret_cast<const uint2*>(P + (size_t)src * (4 * DIN))[col];
      }
  };

  loadpf(0, 0);  // needed immediately at t=0

  // Persistent Whh B-fragments: rows g*DIN + col. Pinned (AGPR-resident).
  bf16x8 Bp[4][KB];
#pragma unroll
  for (int g = 0; g < 4; ++g)
#pragma unroll
    for (int kb = 0; kb < KB; ++kb) {
      Bp[g][kb] =
          ldb8(Whh + (size_t)(g * DIN + col) * DIN + kb * 32 + quad * 8);
      pin(Bp[g][kb]);
    }

  loadpf(1, 1);  // prefetch step 1

  float cst[NT][4];
#pragma unroll
  for (int nt = 0; nt < NT; ++nt)
#pragma unroll
    for (int r = 0; r < 4; ++r) cst[nt][r] = 0.f;

  // Accumulator init = gate pre-activations (C=pf).
  auto initag = [&](int b, int nt, f32x4 (&ag)[4]) {
#pragma unroll
    for (int r = 0; r < 4; ++r) {
      ag[0][r] = b2f_lo(pf[b][nt][r].x);
      ag[1][r] = b2f_hi(pf[b][nt][r].x);
      ag[2][r] = b2f_lo(pf[b][nt][r].y);
      ag[3][r] = b2f_hi(pf[b][nt][r].y);
    }
  };

  // gates: element (node m = nt*16 + quad*4+r, col); ag includes pre-acts.
  auto gates = [&](int hb, int nt, const f32x4 (&ag)[4]) {
#pragma unroll
    for (int r = 0; r < 4; ++r) {
      float cc =
          sigf(ag[1][r]) * cst[nt][r] + sigf(ag[0][r]) * tanhf_(ag[2][r]);
      cst[nt][r] = cc;
      hl[hb][(nt * 16 + quad * 4 + r) * HS + col] =
          __float2bfloat16(sigf(ag[3][r]) * tanhf_(cc));
    }
  };

  // t = 0: h == 0 -> gates directly from pre-acts.
#pragma unroll
  for (int nt = 0; nt < NT; ++nt) {
    f32x4 ag[4];
    initag(0, nt, ag);
    gates(0, nt, ag);
  }

#pragma unroll
  for (int t = 1; t < KNE; ++t) {  // FULL unroll: all pf/hl indices static
    __syncthreads();  // h(t-1) visible
    if (t + 1 < KNE) loadpf(t + 1, (t + 1) & 1);
    const int pb = (t - 1) & 1;
#pragma unroll
    for (int nt = 0; nt < NT; ++nt) {
      bf16x8 Af[KB];
#pragma unroll
      for (int kb = 0; kb < KB; ++kb)
        Af[kb] = ldb8(&hl[pb][(nt * 16 + c16) * HS + kb * 32 + quad * 8]);
      f32x4 ag[4];
      initag(t & 1, nt, ag);
#pragma unroll
      for (int kb = 0; kb < KB; ++kb)
#pragma unroll
        for (int g = 0; g < 4; ++g)
          ag[g] = __builtin_amdgcn_mfma_f32_16x16x32_bf16(Af[kb], Bp[g][kb],
                                                          ag[g], 0, 0, 0);
      gates(t & 1, nt, ag);
    }
  }

  const f32x4 zz = {0.f, 0.f, 0.f, 0.f};
  __syncthreads();  // final h (hl[1], 15&1==1) visible
  bf16x8 Hf[NT][KB];
#pragma unroll
  for (int nt = 0; nt < NT; ++nt)
#pragma unroll
    for (int kb = 0; kb < KB; ++kb)
      Hf[nt][kb] = ldb8(&hl[1][(nt * 16 + c16) * HS + kb * 32 + quad * 8]);
  for (int ct = wv; ct < DOUT / 16; ct += W) {
    f32x4 a[NT];
#pragma unroll
    for (int nt = 0; nt < NT; ++nt) a[nt] = zz;
#pragma unroll
    for (int kb = 0; kb < KB; ++kb) {
      bf16x8 b = ldb8(Wng + (size_t)(ct * 16 + c16) * DIN + kb * 32 + quad * 8);
#pragma unroll
      for (int nt = 0; nt < NT; ++nt)
        a[nt] = __builtin_amdgcn_mfma_f32_16x16x32_bf16(Hf[nt][kb], b, a[nt],
                                                        0, 0, 0);
    }
#pragma unroll
    for (int nt = 0; nt < NT; ++nt)
#pragma unroll
      for (int r = 0; r < 4; ++r) {
        int n = n0 + nt * 16 + quad * 4 + r;
        int c = ct * 16 + c16;
        float v = a[nt][r] + S[(size_t)n * DOUT + c];
        if (RELU) v = fmaxf(v, 0.f);
        if constexpr (sizeof(OutT) == 2)
          outp[(size_t)n * DOUT + c] = __float2bfloat16(v);
        else
          outp[(size_t)n * DOUT + c] = v;
      }
  }
}

extern "C" void kernel_launch(void* const* d_in, const int* in_sizes, int n_in,
                              void* d_out, int out_size, void* d_ws,
                              size_t ws_size, hipStream_t stream) {
  (void)in_sizes; (void)n_in; (void)out_size; (void)ws_size;
  const float* p = (const float*)d_in[0];
  const int* nidx = (const int*)d_in[1];
  const float* L[3][7];
  for (int l = 0; l < 3; ++l)
    for (int j = 0; j < 7; ++j)
      L[l][j] = (const float*)d_in[2 + 7 * l + j];
  // per-layer params: 0=Wih 1=Whh 2=bih 3=bhh 4=Wself 5=Wneigh 6=b

  char* w = (char*)d_ws;
  __hip_bfloat16* feat0 = (__hip_bfloat16*)(w);             // N*64*2  = 2.56MB
  __hip_bfloat16* feat1 = (__hip_bfloat16*)(w + 2560000);   // N*128*2 = 5.12MB
  __hip_bfloat16* feat2 = (__hip_bfloat16*)(w + 7680000);   // N*128*2 = 5.12MB
  __hip_bfloat16* Pb    = (__hip_bfloat16*)(w + 12800000);  // N*512*2 = 20.48MB
  float*          Sb    = (float*)(w + 33280000);           // N*128*4 = 10.24MB
  __hip_bfloat16* wb    = (__hip_bfloat16*)(w + 43520000);  // bf16 weights

  const int din_[3] = {64, 128, 128}, dout_[3] = {128, 128, 32};
  __hip_bfloat16 *Wih_b[3], *Whh_b[3], *Wself_b[3], *Wng_b[3];
  CvtArgs ca;
  size_t off = 0;
  int k = 0, pre = 0;
  for (int l = 0; l < 3; ++l) {
    int din = din_[l], dout = dout_[l];
    int n0 = 4 * din * din, n2 = dout * din;
    Wih_b[l] = wb + off;   off += (size_t)n0;
    Whh_b[l] = wb + off;   off += (size_t)n0;
    Wself_b[l] = wb + off; off += (size_t)n2;
    Wng_b[l] = wb + off;   off += (size_t)n2;
    const float* srcs[4] = {L[l][0], L[l][1], L[l][4], L[l][5]};
    __hip_bfloat16* dsts[4] = {Wih_b[l], Whh_b[l], Wself_b[l], Wng_b[l]};
    int ns[4] = {n0, n0, n2, n2};
    for (int j = 0; j < 4; ++j) {
      ca.s[k] = srcs[j];
      ca.d[k] = dsts[j];
      ca.off[k] = pre;
      pre += ns[j];
      ++k;
    }
  }
  ca.off[12] = pre;

  cvt_all<<<(pre + 255) / 256, 256, 0, stream>>>(ca);
  build_feat0<<<(N_NODES * 64 + 255) / 256, 256, 0, stream>>>(p, feat0);

  // layer 0: din=64, dout=128  (lstm: 4 waves, 32 nodes/block)
  proj_kern<64, 128><<<N_NODES / 32, 256, 0, stream>>>(
      feat0, Wih_b[0], L[0][2], L[0][3], Wself_b[0], L[0][6], Pb, Sb);
  lstm_fc_kern<64, 128, 2, true, __hip_bfloat16>
      <<<N_NODES / 32, 256, 0, stream>>>(Pb, Sb, Whh_b[0], Wng_b[0], nidx,
                                         feat1);

  // layer 1: din=128, dout=128  (lstm: 8 waves, 16 nodes/block)
  proj_kern<128, 128><<<N_NODES / 32, 256, 0, stream>>>(
      feat1, Wih_b[1], L[1][2], L[1][3], Wself_b[1], L[1][6], Pb, Sb);
  lstm_fc_kern<128, 128, 1, true, __hip_bfloat16>
      <<<N_NODES / 16, 512, 0, stream>>>(Pb, Sb, Whh_b[1], Wng_b[1], nidx,
                                         feat2);

  // layer 2: din=128, dout=32 (no relu; final fp32 output)
  proj_kern<128, 32><<<N_NODES / 32, 256, 0, stream>>>(
      feat2, Wih_b[2], L[2][2], L[2][3], Wself_b[2], L[2][6], Pb, Sb);
  lstm_fc_kern<128, 32, 1, false, float>
      <<<N_NODES / 16, 512, 0, stream>>>(Pb, Sb, Whh_b[2], Wng_b[2], nidx,
                                         (float*)d_out);
}

// Round 13
// 324.366 us; speedup vs baseline: 1.0703x; 1.0703x over previous
//
#include <hip/hip_runtime.h>
#include <hip/hip_bf16.h>
#include <stdint.h>

// Net_61272003445332: GraphSAGE w/ LSTM aggregator, N=20000, K=16,
// dims: l0 (din=64,dout=128), l1 (128,128), l2 (128,32).
// R12: (a) 5-dispatch fused pipeline: [cvt] [feat0+proj0] [lstm0+proj1]
//      [lstm1+proj2] [lstm2->out]. fc-out rows a block computes are the proj
//      input rows for the same nodes -> proj phase runs in-kernel off an LDS
//      staging buffer; feat1/feat2 never materialize.
//      (b) gate constants pre-scaled into Wih/Whh/biases/P in cvt_all:
//      i,f,o rows x(-log2e), g rows x(+2log2e) -> sig(x)=rcp(1+exp2(xhat)),
//      saving 4 full-rate muls/element in the hot gate math.

#define N_NODES 20000
#define KNE 16
#define C1F 1.442695041f
#define C2F 2.885390082f

typedef __bf16 bf16x8 __attribute__((ext_vector_type(8)));
typedef float f32x4 __attribute__((ext_vector_type(4)));

__device__ __forceinline__ bf16x8 ldb8(const __hip_bfloat16* p) {
  uint4 u = *reinterpret_cast<const uint4*>(p);
  return __builtin_bit_cast(bf16x8, u);
}
__device__ __forceinline__ void pin(bf16x8& v) {
  uint4 u = __builtin_bit_cast(uint4, v);
  asm volatile("" : "+v"(u.x), "+v"(u.y), "+v"(u.z), "+v"(u.w));
  v = __builtin_bit_cast(bf16x8, u);
}
__device__ __forceinline__ float b2f_lo(uint32_t u) {
  return __builtin_bit_cast(float, u << 16);
}
__device__ __forceinline__ float b2f_hi(uint32_t u) {
  return __builtin_bit_cast(float, u & 0xffff0000u);
}
__device__ __forceinline__ uint32_t pk2(float a, float b) {
  uint32_t ua = (uint32_t)__builtin_bit_cast(unsigned short, __float2bfloat16(a));
  uint32_t ub = (uint32_t)__builtin_bit_cast(unsigned short, __float2bfloat16(b));
  return ua | (ub << 16);
}

// All 12 weight tensors fp32->bf16 in one launch, with per-gate prescale
// for Wih/Whh (gsz = din*din; gate = j/gsz; g==2 -> +C2F else -C1F).
struct CvtArgs {
  const float* s[12];
  __hip_bfloat16* d[12];
  int off[13];
  int gsz[12];
};
__global__ void cvt_all(CvtArgs a) {
  int i = blockIdx.x * 256 + threadIdx.x;
  if (i >= a.off[12]) return;
#pragma unroll
  for (int k = 0; k < 12; ++k)
    if (i >= a.off[k] && i < a.off[k + 1]) {
      int j = i - a.off[k];
      float v = a.s[k][j];
      if (a.gsz[k]) {
        int g = j / a.gsz[k];
        v *= (g == 2) ? C2F : -C1F;
      }
      a.d[k][j] = __float2bfloat16(v);
    }
}

// Shared proj phase: reads A rows (16*NTR x DIN) from LDS (stride DIN+8),
// writes gate-packed prescaled P [N][DIN][4] and S=f@Wself.T+b [N][DOUT].
template <int DIN, int DOUT, int NTR, int WW>
__device__ __forceinline__ void proj_phase(
    const __hip_bfloat16* sA,
    const __hip_bfloat16* __restrict__ Wih,
    const float* __restrict__ bih, const float* __restrict__ bhh,
    const __hip_bfloat16* __restrict__ Wself,
    const float* __restrict__ bvec,
    __hip_bfloat16* __restrict__ P, float* __restrict__ S,
    int n0, int wv, int quad, int c16) {
  constexpr int KB = DIN / 32;
  constexpr int CCT = DIN / 16;
  constexpr int CTS = DOUT / 16;
  constexpr int HS = DIN + 8;
  const f32x4 zz = {0.f, 0.f, 0.f, 0.f};
  bf16x8 afr[NTR][KB];
#pragma unroll
  for (int nt = 0; nt < NTR; ++nt)
#pragma unroll
    for (int kb = 0; kb < KB; ++kb)
      afr[nt][kb] = ldb8(&sA[(nt * 16 + c16) * HS + kb * 32 + quad * 8]);

  for (int ct = wv; ct < CCT + CTS; ct += WW) {
    if (ct < CCT) {
      const int cc = ct * 16 + c16;
      f32x4 ag[4][NTR];
#pragma unroll
      for (int g = 0; g < 4; ++g)
#pragma unroll
        for (int nt = 0; nt < NTR; ++nt) ag[g][nt] = zz;
#pragma unroll
      for (int kb = 0; kb < KB; ++kb)
#pragma unroll
        for (int g = 0; g < 4; ++g) {
          bf16x8 b =
              ldb8(Wih + (size_t)(g * DIN + cc) * DIN + kb * 32 + quad * 8);
#pragma unroll
          for (int nt = 0; nt < NTR; ++nt)
            ag[g][nt] = __builtin_amdgcn_mfma_f32_16x16x32_bf16(
                afr[nt][kb], b, ag[g][nt], 0, 0, 0);
        }
      float bi = -C1F * (bih[cc] + bhh[cc]);
      float bf_ = -C1F * (bih[DIN + cc] + bhh[DIN + cc]);
      float bg = C2F * (bih[2 * DIN + cc] + bhh[2 * DIN + cc]);
      float bo = -C1F * (bih[3 * DIN + cc] + bhh[3 * DIN + cc]);
      uint2* Pp = reinterpret_cast<uint2*>(P);
#pragma unroll
      for (int nt = 0; nt < NTR; ++nt)
#pragma unroll
        for (int r = 0; r < 4; ++r) {
          int n = n0 + nt * 16 + quad * 4 + r;
          uint2 u;
          u.x = pk2(ag[0][nt][r] + bi, ag[1][nt][r] + bf_);
          u.y = pk2(ag[2][nt][r] + bg, ag[3][nt][r] + bo);
          Pp[(size_t)n * DIN + cc] = u;
        }
    } else {
      const int c = (ct - CCT) * 16 + c16;
      f32x4 a[NTR];
#pragma unroll
      for (int nt = 0; nt < NTR; ++nt) a[nt] = zz;
#pragma unroll
      for (int kb = 0; kb < KB; ++kb) {
        bf16x8 b = ldb8(Wself + (size_t)c * DIN + kb * 32 + quad * 8);
#pragma unroll
        for (int nt = 0; nt < NTR; ++nt)
          a[nt] = __builtin_amdgcn_mfma_f32_16x16x32_bf16(afr[nt][kb], b,
                                                          a[nt], 0, 0, 0);
      }
      float bias = bvec[c];
#pragma unroll
      for (int nt = 0; nt < NTR; ++nt)
#pragma unroll
        for (int r = 0; r < 4; ++r)
          S[(size_t)(n0 + nt * 16 + quad * 4 + r) * DOUT + c] =
              a[nt][r] + bias;
    }
  }
}

// Dispatch 2: build feat0 in LDS (deg prepend) + proj layer 0.
__global__ __launch_bounds__(256, 2) void feat_proj0(
    const float* __restrict__ p,
    const __hip_bfloat16* __restrict__ Wih,
    const float* __restrict__ bih, const float* __restrict__ bhh,
    const __hip_bfloat16* __restrict__ Wself,
    const float* __restrict__ bvec,
    __hip_bfloat16* __restrict__ P, float* __restrict__ S) {
  __shared__ __align__(16) __hip_bfloat16 sFeat[32 * 72];
  const int n0 = blockIdx.x * 32;
  const int tid = threadIdx.x;
  const int wv = tid >> 6;
  const int lane = tid & 63;
  const int quad = lane >> 4;
  const int c16 = lane & 15;

  for (int i = tid; i < 32 * 64; i += 256) {
    int n = i >> 6, c = i & 63;
    float v = (c == 0) ? ((float)KNE / (float)N_NODES)
                       : p[(size_t)(n0 + n) * 63 + c - 1];
    sFeat[n * 72 + c] = __float2bfloat16(v);
  }
  __syncthreads();
  proj_phase<64, 128, 2, 4>(sFeat, Wih, bih, bhh, Wself, bvec, P, S, n0, wv,
                            quad, c16);
}

// LSTM (prescaled gates) + fused fc -> LDS staging -> proj of next layer.
// Block = (DIN/16) waves, NT 16-node row-tiles.
template <int DIN, int DOUT, int DOUTN, int NT, bool RELU>
__global__ __launch_bounds__((DIN / 16) * 64)
__attribute__((amdgpu_waves_per_eu(4))) void lstm_proj_kern(
    const __hip_bfloat16* __restrict__ P,   // [N][DIN][4] prescaled bf16
    const float* __restrict__ S,            // [N, DOUT] f32
    const __hip_bfloat16* __restrict__ Whh, // prescaled bf16 [4*DIN, DIN]
    const __hip_bfloat16* __restrict__ Wng, // bf16 [DOUT, DIN]
    const int* __restrict__ nidx,
    const __hip_bfloat16* __restrict__ Wih2,  // next-layer proj params
    const float* __restrict__ bih2, const float* __restrict__ bhh2,
    const __hip_bfloat16* __restrict__ Wself2,
    const float* __restrict__ bvec2,
    __hip_bfloat16* __restrict__ P2, float* __restrict__ S2) {
  constexpr int W = DIN / 16;
  constexpr int KB = DIN / 32;
  constexpr int HS = DIN + 8;
  constexpr int NN = 16 * NT;
  constexpr int HS2 = DOUT + 8;

  __shared__ __align__(16) __hip_bfloat16 hl[2][NN * HS];
  __shared__ __align__(16) __hip_bfloat16 sOut[NN * HS2];
  __shared__ int idxl[NN * KNE];

  const int n0 = blockIdx.x * NN;
  const int tid = threadIdx.x;
  const int wv = tid >> 6;
  const int lane = tid & 63;
  const int quad = lane >> 4;
  const int c16 = lane & 15;
  const int col = wv * 16 + c16;

  for (int i = tid; i < NN * KNE; i += W * 64) idxl[i] = nidx[n0 * KNE + i];
  __syncthreads();

  uint2 pf[2][NT][4];
  auto loadpf = [&](int t, int b) {
#pragma unroll
    for (int nt = 0; nt < NT; ++nt)
#pragma unroll
      for (int r = 0; r < 4; ++r) {
        int src = idxl[(nt * 16 + quad * 4 + r) * KNE + t];
        pf[b][nt][r] =
            reinterpret_cast<const uint2*>(P + (size_t)src * (4 * DIN))[col];
      }
  };

  loadpf(0, 0);

  bf16x8 Bp[4][KB];
#pragma unroll
  for (int g = 0; g < 4; ++g)
#pragma unroll
    for (int kb = 0; kb < KB; ++kb) {
      Bp[g][kb] =
          ldb8(Whh + (size_t)(g * DIN + col) * DIN + kb * 32 + quad * 8);
      pin(Bp[g][kb]);
    }

  loadpf(1, 1);

  float cst[NT][4];
#pragma unroll
  for (int nt = 0; nt < NT; ++nt)
#pragma unroll
    for (int r = 0; r < 4; ++r) cst[nt][r] = 0.f;

  auto initag = [&](int b, int nt, f32x4 (&ag)[4]) {
#pragma unroll
    for (int r = 0; r < 4; ++r) {
      ag[0][r] = b2f_lo(pf[b][nt][r].x);
      ag[1][r] = b2f_hi(pf[b][nt][r].x);
      ag[2][r] = b2f_lo(pf[b][nt][r].y);
      ag[3][r] = b2f_hi(pf[b][nt][r].y);
    }
  };

  // Prescaled gates: inputs already -C1*x (i,f,o) / +C2*x (g).
  auto gates = [&](int hb, int nt, const f32x4 (&ag)[4]) {
#pragma unroll
    for (int r = 0; r < 4; ++r) {
      float wi = __builtin_amdgcn_rcpf(1.f + __builtin_amdgcn_exp2f(ag[0][r]));
      float wf = __builtin_amdgcn_rcpf(1.f + __builtin_amdgcn_exp2f(ag[1][r]));
      float wg = __builtin_amdgcn_rcpf(1.f + __builtin_amdgcn_exp2f(ag[2][r]));
      float wo = __builtin_amdgcn_rcpf(1.f + __builtin_amdgcn_exp2f(ag[3][r]));
      float tg = fmaf(-2.f, wg, 1.f);
      float cc = wf * cst[nt][r] + wi * tg;
      cst[nt][r] = cc;
      float tc = fmaf(
          -2.f,
          __builtin_amdgcn_rcpf(1.f + __builtin_amdgcn_exp2f(C2F * cc)), 1.f);
      hl[hb][(nt * 16 + quad * 4 + r) * HS + col] =
          __float2bfloat16(wo * tc);
    }
  };

#pragma unroll
  for (int nt = 0; nt < NT; ++nt) {
    f32x4 ag[4];
    initag(0, nt, ag);
    gates(0, nt, ag);
  }

#pragma unroll
  for (int t = 1; t < KNE; ++t) {
    __syncthreads();
    if (t + 1 < KNE) loadpf(t + 1, (t + 1) & 1);
    const int pb = (t - 1) & 1;
#pragma unroll
    for (int nt = 0; nt < NT; ++nt) {
      bf16x8 Af[KB];
#pragma unroll
      for (int kb = 0; kb < KB; ++kb)
        Af[kb] = ldb8(&hl[pb][(nt * 16 + c16) * HS + kb * 32 + quad * 8]);
      f32x4 ag[4];
      initag(t & 1, nt, ag);
#pragma unroll
      for (int kb = 0; kb < KB; ++kb)
#pragma unroll
        for (int g = 0; g < 4; ++g)
          ag[g] = __builtin_amdgcn_mfma_f32_16x16x32_bf16(Af[kb], Bp[g][kb],
                                                          ag[g], 0, 0, 0);
      gates(t & 1, nt, ag);
    }
  }

  const f32x4 zz = {0.f, 0.f, 0.f, 0.f};
  __syncthreads();  // final h in hl[1]
  bf16x8 Hf[NT][KB];
#pragma unroll
  for (int nt = 0; nt < NT; ++nt)
#pragma unroll
    for (int kb = 0; kb < KB; ++kb)
      Hf[nt][kb] = ldb8(&hl[1][(nt * 16 + c16) * HS + kb * 32 + quad * 8]);
  for (int ct = wv; ct < DOUT / 16; ct += W) {
    f32x4 a[NT];
#pragma unroll
    for (int nt = 0; nt < NT; ++nt) a[nt] = zz;
#pragma unroll
    for (int kb = 0; kb < KB; ++kb) {
      bf16x8 b = ldb8(Wng + (size_t)(ct * 16 + c16) * DIN + kb * 32 + quad * 8);
#pragma unroll
      for (int nt = 0; nt < NT; ++nt)
        a[nt] = __builtin_amdgcn_mfma_f32_16x16x32_bf16(Hf[nt][kb], b, a[nt],
                                                        0, 0, 0);
    }
#pragma unroll
    for (int nt = 0; nt < NT; ++nt)
#pragma unroll
      for (int r = 0; r < 4; ++r) {
        int n = n0 + nt * 16 + quad * 4 + r;
        int c = ct * 16 + c16;
        float v = a[nt][r] + S[(size_t)n * DOUT + c];
        if (RELU) v = fmaxf(v, 0.f);
        sOut[(nt * 16 + quad * 4 + r) * HS2 + c] = __float2bfloat16(v);
      }
  }
  __syncthreads();  // staging ready
  proj_phase<DOUT, DOUTN, NT, W>(sOut, Wih2, bih2, bhh2, Wself2, bvec2, P2,
                                 S2, n0, wv, quad, c16);
}

// Final layer: LSTM + fc -> f32 d_out (no proj).
template <int DIN, int DOUT>
__global__ __launch_bounds__((DIN / 16) * 64)
__attribute__((amdgpu_waves_per_eu(4))) void lstm_out_kern(
    const __hip_bfloat16* __restrict__ P, const float* __restrict__ S,
    const __hip_bfloat16* __restrict__ Whh,
    const __hip_bfloat16* __restrict__ Wng, const int* __restrict__ nidx,
    float* __restrict__ outp) {
  constexpr int W = DIN / 16;
  constexpr int KB = DIN / 32;
  constexpr int HS = DIN + 8;

  __shared__ __align__(16) __hip_bfloat16 hl[2][16 * HS];
  __shared__ int idxl[16 * KNE];

  const int n0 = blockIdx.x * 16;
  const int tid = threadIdx.x;
  const int wv = tid >> 6;
  const int lane = tid & 63;
  const int quad = lane >> 4;
  const int c16 = lane & 15;
  const int col = wv * 16 + c16;

  for (int i = tid; i < 16 * KNE; i += W * 64) idxl[i] = nidx[n0 * KNE + i];
  __syncthreads();

  uint2 pf[2][4];
  auto loadpf = [&](int t, int b) {
#pragma unroll
    for (int r = 0; r < 4; ++r) {
      int src = idxl[(quad * 4 + r) * KNE + t];
      pf[b][r] =
          reinterpret_cast<const uint2*>(P + (size_t)src * (4 * DIN))[col];
    }
  };

  loadpf(0, 0);
  bf16x8 Bp[4][KB];
#pragma unroll
  for (int g = 0; g < 4; ++g)
#pragma unroll
    for (int kb = 0; kb < KB; ++kb) {
      Bp[g][kb] =
          ldb8(Whh + (size_t)(g * DIN + col) * DIN + kb * 32 + quad * 8);
      pin(Bp[g][kb]);
    }
  loadpf(1, 1);

  float cst[4];
#pragma unroll
  for (int r = 0; r < 4; ++r) cst[r] = 0.f;

  auto initag = [&](int b, f32x4 (&ag)[4]) {
#pragma unroll
    for (int r = 0; r < 4; ++r) {
      ag[0][r] = b2f_lo(pf[b][r].x);
      ag[1][r] = b2f_hi(pf[b][r].x);
      ag[2][r] = b2f_lo(pf[b][r].y);
      ag[3][r] = b2f_hi(pf[b][r].y);
    }
  };
  auto gates = [&](int hb, const f32x4 (&ag)[4]) {
#pragma unroll
    for (int r = 0; r < 4; ++r) {
      float wi = __builtin_amdgcn_rcpf(1.f + __builtin_amdgcn_exp2f(ag[0][r]));
      float wf = __builtin_amdgcn_rcpf(1.f + __builtin_amdgcn_exp2f(ag[1][r]));
      float wg = __builtin_amdgcn_rcpf(1.f + __builtin_amdgcn_exp2f(ag[2][r]));
      float wo = __builtin_amdgcn_rcpf(1.f + __builtin_amdgcn_exp2f(ag[3][r]));
      float tg = fmaf(-2.f, wg, 1.f);
      float cc = wf * cst[r] + wi * tg;
      cst[r] = cc;
      float tc = fmaf(
          -2.f,
          __builtin_amdgcn_rcpf(1.f + __builtin_amdgcn_exp2f(C2F * cc)), 1.f);
      hl[hb][(quad * 4 + r) * HS + col] = __float2bfloat16(wo * tc);
    }
  };

  {
    f32x4 ag[4];
    initag(0, ag);
    gates(0, ag);
  }
#pragma unroll
  for (int t = 1; t < KNE; ++t) {
    __syncthreads();
    if (t + 1 < KNE) loadpf(t + 1, (t + 1) & 1);
    const int pb = (t - 1) & 1;
    bf16x8 Af[KB];
#pragma unroll
    for (int kb = 0; kb < KB; ++kb)
      Af[kb] = ldb8(&hl[pb][c16 * HS + kb * 32 + quad * 8]);
    f32x4 ag[4];
    initag(t & 1, ag);
#pragma unroll
    for (int kb = 0; kb < KB; ++kb)
#pragma unroll
      for (int g = 0; g < 4; ++g)
        ag[g] = __builtin_amdgcn_mfma_f32_16x16x32_bf16(Af[kb], Bp[g][kb],
                                                        ag[g], 0, 0, 0);
    gates(t & 1, ag);
  }

  const f32x4 zz = {0.f, 0.f, 0.f, 0.f};
  __syncthreads();
  bf16x8 Hf[KB];
#pragma unroll
  for (int kb = 0; kb < KB; ++kb)
    Hf[kb] = ldb8(&hl[1][c16 * HS + kb * 32 + quad * 8]);
  for (int ct = wv; ct < DOUT / 16; ct += W) {
    f32x4 a = zz;
#pragma unroll
    for (int kb = 0; kb < KB; ++kb) {
      bf16x8 b = ldb8(Wng + (size_t)(ct * 16 + c16) * DIN + kb * 32 + quad * 8);
      a = __builtin_amdgcn_mfma_f32_16x16x32_bf16(Hf[kb], b, a, 0, 0, 0);
    }
#pragma unroll
    for (int r = 0; r < 4; ++r) {
      int n = n0 + quad * 4 + r;
      int c = ct * 16 + c16;
      outp[(size_t)n * DOUT + c] = a[r] + S[(size_t)n * DOUT + c];
    }
  }
}

extern "C" void kernel_launch(void* const* d_in, const int* in_sizes, int n_in,
                              void* d_out, int out_size, void* d_ws,
                              size_t ws_size, hipStream_t stream) {
  (void)in_sizes; (void)n_in; (void)out_size; (void)ws_size;
  const float* p = (const float*)d_in[0];
  const int* nidx = (const int*)d_in[1];
  const float* L[3][7];
  for (int l = 0; l < 3; ++l)
    for (int j = 0; j < 7; ++j)
      L[l][j] = (const float*)d_in[2 + 7 * l + j];
  // per-layer params: 0=Wih 1=Whh 2=bih 3=bhh 4=Wself 5=Wneigh 6=b

  char* w = (char*)d_ws;
  __hip_bfloat16* P0 = (__hip_bfloat16*)(w);               // N*256*2 = 10.24MB
  float*          S0 = (float*)(w + 10240000);             // N*128*4 = 10.24MB
  __hip_bfloat16* P1 = (__hip_bfloat16*)(w + 20480000);    // N*512*2 = 20.48MB
  float*          S1 = (float*)(w + 40960000);             // N*128*4 = 10.24MB
  float*          S2 = (float*)(w + 51200000);             // N*32*4  = 2.56MB
  __hip_bfloat16* P2 = (__hip_bfloat16*)(w);               // aliases dead P0+S0
  __hip_bfloat16* wb = (__hip_bfloat16*)(w + 53760000);    // bf16 weights

  const int din_[3] = {64, 128, 128}, dout_[3] = {128, 128, 32};
  __hip_bfloat16 *Wih_b[3], *Whh_b[3], *Wself_b[3], *Wng_b[3];
  CvtArgs ca;
  size_t off = 0;
  int k = 0, pre = 0;
  for (int l = 0; l < 3; ++l) {
    int din = din_[l], dout = dout_[l];
    int n0 = 4 * din * din, n2 = dout * din;
    Wih_b[l] = wb + off;   off += (size_t)n0;
    Whh_b[l] = wb + off;   off += (size_t)n0;
    Wself_b[l] = wb + off; off += (size_t)n2;
    Wng_b[l] = wb + off;   off += (size_t)n2;
    const float* srcs[4] = {L[l][0], L[l][1], L[l][4], L[l][5]};
    __hip_bfloat16* dsts[4] = {Wih_b[l], Whh_b[l], Wself_b[l], Wng_b[l]};
    int ns[4] = {n0, n0, n2, n2};
    int gs[4] = {din * din, din * din, 0, 0};
    for (int j = 0; j < 4; ++j) {
      ca.s[k] = srcs[j];
      ca.d[k] = dsts[j];
      ca.off[k] = pre;
      ca.gsz[k] = gs[j];
      pre += ns[j];
      ++k;
    }
  }
  ca.off[12] = pre;

  cvt_all<<<(pre + 255) / 256, 256, 0, stream>>>(ca);

  // layer 0 proj (+feat0 build in LDS)
  feat_proj0<<<N_NODES / 32, 256, 0, stream>>>(
      p, Wih_b[0], L[0][2], L[0][3], Wself_b[0], L[0][6], P0, S0);

  // lstm layer 0 + proj layer 1
  lstm_proj_kern<64, 128, 128, 2, true><<<N_NODES / 32, 256, 0, stream>>>(
      P0, S0, Whh_b[0], Wng_b[0], nidx, Wih_b[1], L[1][2], L[1][3],
      Wself_b[1], L[1][6], P1, S1);

  // lstm layer 1 + proj layer 2
  lstm_proj_kern<128, 128, 32, 1, true><<<N_NODES / 16, 512, 0, stream>>>(
      P1, S1, Whh_b[1], Wng_b[1], nidx, Wih_b[2], L[2][2], L[2][3],
      Wself_b[2], L[2][6], P2, S2);

  // lstm layer 2 -> final f32 output
  lstm_out_kern<128, 32><<<N_NODES / 16, 512, 0, stream>>>(
      P2, S2, Whh_b[2], Wng_b[2], nidx, (float*)d_out);
}